// Round 2
// baseline (1591.190 us; speedup 1.0000x reference)
//
#include <hip/hip_runtime.h>
#include <cstdio>
#include <cstdint>

typedef unsigned short u16;
typedef short short8 __attribute__((ext_vector_type(8)));
typedef float floatx4 __attribute__((ext_vector_type(4)));

#define NPIX 16384      // 128*128
#define DIM 256

__device__ inline float bf2f(u16 v) {
    return __uint_as_float(((uint32_t)v) << 16);
}
__device__ inline u16 f2bf(float f) {
    uint32_t u = __float_as_uint(f);
    u += 0x7fffu + ((u >> 16) & 1u);
    return (u16)(u >> 16);
}
__device__ inline float gelu_tanh(float x) {
    float x3 = x * x * x;
    return 0.5f * x * (1.f + tanhf(0.7978845608028654f * (x + 0.044715f * x3)));
}
// flag-aware load of 8 consecutive elements from a raw input tensor
__device__ inline void load8(const u16* p, size_t idx, int isf32, float out[8]) {
    if (isf32) {
        const float4* f = (const float4*)((const float*)p + idx);
        float4 a = f[0], b = f[1];
        out[0] = a.x; out[1] = a.y; out[2] = a.z; out[3] = a.w;
        out[4] = b.x; out[5] = b.y; out[6] = b.z; out[7] = b.w;
    } else {
        uint4 d = *(const uint4*)(p + idx);
        u16 v[8]; *(uint4*)v = d;
#pragma unroll
        for (int j = 0; j < 8; ++j) out[j] = bf2f(v[j]);
    }
}

// ---------------- dtype sniffer: low u16 of each word is a plausible bf16 only for bf16 data
__global__ __launch_bounds__(256)
void detect_dtype(const u16* __restrict__ x, int* __restrict__ flag) {
    __shared__ int sh[256];
    int t = threadIdx.x;
    const uint32_t* w = (const uint32_t*)x;
    int cnt = 0;
    for (int i = t; i < 4096; i += 256) {
        int e = (w[i] >> 7) & 0xFF;
        if (e >= 110 && e <= 134) cnt++;
    }
    sh[t] = cnt;
    __syncthreads();
    if (t == 0) {
        int s = 0;
        for (int i = 0; i < 256; ++i) s += sh[i];
        *flag = (s < 2048) ? 1 : 0;    // 1 => inputs are float32
    }
}

// ---------------- convert all parameter tensors to canonical bf16 in ws
struct WArgs {
    const void* src[17];
    int off[17];
    int n[17];
};
__global__ __launch_bounds__(256)
void convert_params(WArgs a, const int* __restrict__ flag, u16* __restrict__ dst) {
    int isf32 = *flag;
    int w = blockIdx.y;
    const void* s = a.src[w];
    u16* d = dst + a.off[w];
    int n = a.n[w];
    for (int i = blockIdx.x * 256 + threadIdx.x; i < n; i += gridDim.x * 256)
        d[i] = isf32 ? f2bf(((const float*)s)[i]) : ((const u16*)s)[i];
}

// ---------------- LN stats: per-pixel mean/rstd over 256 channels (NCHW input)
__global__ __launch_bounds__(256)
void ln_stats(const u16* __restrict__ x, const int* __restrict__ flag,
              float* __restrict__ mu, float* __restrict__ rstd) {
    int isf32 = *flag;
    int g = blockIdx.x * 256 + threadIdx.x;       // pixel id 0..131071
    int b = g >> 14, n = g & (NPIX - 1);
    float s = 0.f, s2 = 0.f;
    if (isf32) {
        const float* p = (const float*)x + (size_t)b * DIM * NPIX + n;
        for (int c = 0; c < DIM; ++c) { float v = p[(size_t)c * NPIX]; s += v; s2 += v * v; }
    } else {
        const u16* p = x + (size_t)b * DIM * NPIX + n;
        for (int c = 0; c < DIM; ++c) { float v = bf2f(p[(size_t)c * NPIX]); s += v; s2 += v * v; }
    }
    float m = s * (1.f / 256.f);
    float var = s2 * (1.f / 256.f) - m * m;
    mu[g] = m;
    rstd[g] = rsqrtf(var + 1e-5f);
}

// ---------------- LN + transpose NCHW -> NHWC (bf16 out)
__global__ __launch_bounds__(256)
void ln_transpose(const u16* __restrict__ x, const int* __restrict__ flag,
                  const float* __restrict__ mu, const float* __restrict__ rstd,
                  const u16* __restrict__ lnw, const u16* __restrict__ lnb,
                  u16* __restrict__ xt) {
    int isf32 = *flag;
    __shared__ u16 T[64][72];                     // [n_local][c_local], padded
    int b = blockIdx.x >> 8;
    int n0 = (blockIdx.x & 255) * 64;
    int c0 = blockIdx.y * 64;
    int t = threadIdx.x;
#pragma unroll
    for (int l = 0; l < 2; ++l) {
        int idx = t + l * 256;
        int cl = idx >> 3, nch = (idx & 7) * 8;
        float vals[8];
        load8(x, ((size_t)(b * DIM + c0 + cl)) * NPIX + n0 + nch, isf32, vals);
        float w = bf2f(lnw[c0 + cl]), bb = bf2f(lnb[c0 + cl]);
#pragma unroll
        for (int j = 0; j < 8; ++j) {
            int g = b * NPIX + n0 + nch + j;
            float v = (vals[j] - mu[g]) * rstd[g] * w + bb;
            T[nch + j][cl] = f2bf(v);
        }
    }
    __syncthreads();
#pragma unroll
    for (int l = 0; l < 2; ++l) {
        int idx = t + l * 256;
        int nl = idx >> 3, cch = (idx & 7) * 8;
        uint4 d = *(const uint4*)&T[nl][cch];
        *(uint4*)(xt + (size_t)(b * NPIX + n0 + nl) * DIM + c0 + cch) = d;
    }
}

// ---------------- GEMM: C[M][ldc] = A[M][256] @ Bw[Nout][256]^T + bias (+addt)
template <int HAS_ADD>
__global__ __launch_bounds__(256)
void gemm_bf16(const u16* __restrict__ A, const u16* __restrict__ Bw,
               const u16* __restrict__ bias, const u16* __restrict__ addt,
               u16* __restrict__ C, int ldc) {
    __shared__ u16 As[128][40];
    __shared__ u16 Bs[128][40];
    const int m0 = blockIdx.x * 128;
    const int n0 = blockIdx.y * 128;
    const int t = threadIdx.x;
    const int lane = t & 63;
    const int wid = t >> 6;
    const int wm = (wid >> 1) * 64;
    const int wn = (wid & 1) * 64;
    const int frow = lane & 15;
    const int koff = (lane >> 4) * 8;
    floatx4 acc[4][4] = {};
    for (int k0 = 0; k0 < 256; k0 += 32) {
#pragma unroll
        for (int l = 0; l < 2; ++l) {
            int idx = t + l * 256;
            int r = idx >> 2, ch = (idx & 3) * 8;
            *(uint4*)&As[r][ch] = *(const uint4*)(A + (size_t)(m0 + r) * 256 + k0 + ch);
            *(uint4*)&Bs[r][ch] = *(const uint4*)(Bw + (size_t)(n0 + r) * 256 + k0 + ch);
        }
        __syncthreads();
        short8 af[4], bfr[4];
#pragma unroll
        for (int i = 0; i < 4; ++i) {
            af[i] = *(const short8*)&As[wm + i * 16 + frow][koff];
            bfr[i] = *(const short8*)&Bs[wn + i * 16 + frow][koff];
        }
#pragma unroll
        for (int i = 0; i < 4; ++i)
#pragma unroll
            for (int j = 0; j < 4; ++j)
                acc[i][j] = __builtin_amdgcn_mfma_f32_16x16x32_bf16(af[i], bfr[j], acc[i][j], 0, 0, 0);
        __syncthreads();
    }
    const int col = lane & 15;
    const int r0 = (lane >> 4) * 4;
#pragma unroll
    for (int j = 0; j < 4; ++j) {
        int o = n0 + wn + j * 16 + col;
        float bv = bf2f(bias[o]);
#pragma unroll
        for (int i = 0; i < 4; ++i) {
#pragma unroll
            for (int r = 0; r < 4; ++r) {
                int m = m0 + wm + i * 16 + r0 + r;
                size_t off = (size_t)m * ldc + o;
                float v = acc[i][j][r] + bv;
                if (HAS_ADD) v += bf2f(addt[off]);
                C[off] = f2bf(v);
            }
        }
    }
}

// ---------------- depthwise 3x3 SAME, NHWC, optional bias / gelu
__global__ __launch_bounds__(256)
void dwconv3_nhwc(const u16* __restrict__ in, int in_stride, int in_off,
                  const u16* __restrict__ w9, const u16* __restrict__ bias,
                  u16* __restrict__ out, int out_stride, int out_off,
                  int C, int do_gelu) {
    extern __shared__ float wsm[];                 // [9][C]
    int t = threadIdx.x;
    for (int i = t; i < C * 9; i += 256) {
        int c = i / 9, tap = i % 9;
        wsm[tap * C + c] = bf2f(w9[i]);
    }
    __syncthreads();
    const int tpp = C >> 3;                        // threads per pixel
    const int ppb = 256 / tpp;
    int pix = blockIdx.x * ppb + t / tpp;
    int c8 = (t % tpp) * 8;
    int b = pix >> 14, n = pix & (NPIX - 1);
    int y = n >> 7, x = n & 127;
    float acc[8] = {0, 0, 0, 0, 0, 0, 0, 0};
    const u16* base = in + (size_t)(b * NPIX) * in_stride + in_off + c8;
#pragma unroll
    for (int dy = -1; dy <= 1; ++dy) {
        int yy = y + dy;
        if ((unsigned)yy >= 128u) continue;
#pragma unroll
        for (int dx = -1; dx <= 1; ++dx) {
            int xx = x + dx;
            if ((unsigned)xx >= 128u) continue;
            uint4 d = *(const uint4*)(base + (size_t)(yy * 128 + xx) * in_stride);
            u16 v[8]; *(uint4*)v = d;
            int tap = (dy + 1) * 3 + (dx + 1);
            const float4* wp = (const float4*)&wsm[tap * C + c8];
            float4 w0 = wp[0], w1 = wp[1];
            acc[0] += bf2f(v[0]) * w0.x; acc[1] += bf2f(v[1]) * w0.y;
            acc[2] += bf2f(v[2]) * w0.z; acc[3] += bf2f(v[3]) * w0.w;
            acc[4] += bf2f(v[4]) * w1.x; acc[5] += bf2f(v[5]) * w1.y;
            acc[6] += bf2f(v[6]) * w1.z; acc[7] += bf2f(v[7]) * w1.w;
        }
    }
    u16 o[8];
#pragma unroll
    for (int j = 0; j < 8; ++j) {
        float r = acc[j];
        if (bias) r += bf2f(bias[c8 + j]);
        if (do_gelu) r = gelu_tanh(r);
        o[j] = f2bf(r);
    }
    *(uint4*)(out + (size_t)pix * out_stride + out_off + c8) = *(uint4*)o;
}

// ---------------- per (b,c) column sum of squares (channels-last tensor)
__global__ __launch_bounds__(256)
void colsumsq(const u16* __restrict__ in, int stride, int coloff, float* __restrict__ out) {
    int blk = blockIdx.x;                          // 8 b * 32 chunks
    int b = blk >> 5, chunk = blk & 31;
    int c = threadIdx.x;
    const u16* p = in + ((size_t)(b * NPIX + chunk * 512)) * stride + coloff + c;
    float s = 0.f;
    for (int r = 0; r < 512; ++r) {
        float v = bf2f(p[(size_t)r * stride]);
        s += v * v;
    }
    atomicAdd(&out[b * 256 + c], s);
}

__global__ __launch_bounds__(256)
void finalize_scales(const float* __restrict__ qss, const float* __restrict__ kss,
                     float* __restrict__ qsc, float* __restrict__ ksc) {
    int i = blockIdx.x * 256 + threadIdx.x;        // 2048
    qsc[i] = 1.f / fmaxf(sqrtf(qss[i]), 1e-12f);
    ksc[i] = 1.f / fmaxf(sqrtf(kss[i]), 1e-12f);
}

// ---------------- Gram: G[b,h,i,j] = sum_n q[n][h*32+i] * k[n][h*32+j]
__global__ __launch_bounds__(256)
void gram_kernel(const u16* __restrict__ qT, const u16* __restrict__ kvT, float* __restrict__ G) {
    __shared__ u16 qs[8][256];
    __shared__ u16 ks[8][256];
    int b = blockIdx.x >> 5, chunk = blockIdx.x & 31;
    int t = threadIdx.x;
    int h = t >> 5, i = t & 31;
    float acc[32];
#pragma unroll
    for (int j = 0; j < 32; ++j) acc[j] = 0.f;
    int row0 = b * NPIX + chunk * 512;
    int rr = t >> 5, cc = (t & 31) * 8;
    for (int r8 = 0; r8 < 512; r8 += 8) {
        *(uint4*)&qs[rr][cc] = *(const uint4*)(qT + (size_t)(row0 + r8 + rr) * 256 + cc);
        *(uint4*)&ks[rr][cc] = *(const uint4*)(kvT + (size_t)(row0 + r8 + rr) * 512 + cc);
        __syncthreads();
#pragma unroll
        for (int r = 0; r < 8; ++r) {
            float qv = bf2f(qs[r][h * 32 + i]);
#pragma unroll
            for (int j = 0; j < 32; j += 4) {
                uint2 kd = *(const uint2*)&ks[r][h * 32 + j];
                u16 k4[4]; *(uint2*)k4 = kd;
                acc[j]     += qv * bf2f(k4[0]);
                acc[j + 1] += qv * bf2f(k4[1]);
                acc[j + 2] += qv * bf2f(k4[2]);
                acc[j + 3] += qv * bf2f(k4[3]);
            }
        }
        __syncthreads();
    }
    float* Gp = G + ((size_t)(b * 8 + h) * 32 + i) * 32;
    for (int j = 0; j < 32; ++j) atomicAdd(&Gp[j], acc[j]);
}

// ---------------- softmax over j with scales and temperature
__global__ __launch_bounds__(1024)
void softmax32(const float* __restrict__ G, const float* __restrict__ qsc,
               const float* __restrict__ ksc, const u16* __restrict__ temp,
               float* __restrict__ attn) {
    int bh = blockIdx.x;
    int b = bh >> 3, h = bh & 7;
    int t = threadIdx.x;
    int i = t >> 5, j = t & 31;
    float qs = qsc[b * 256 + h * 32 + i];
    float ks = ksc[b * 256 + h * 32 + j];
    float tm = bf2f(temp[h]);
    size_t off = ((size_t)(b * 8 + h) * 32 + i) * 32 + j;
    float v = G[off] * qs * ks * tm;
    float m = v;
    for (int s = 16; s; s >>= 1) m = fmaxf(m, __shfl_xor(m, s, 32));
    float e = __expf(v - m);
    float sum = e;
    for (int s = 16; s; s >>= 1) sum += __shfl_xor(sum, s, 32);
    attn[off] = e / sum;
}

// ---------------- out[n][c] = sum_j attn[h,i,j] * v[n][h*32+j]  (channels-last out)
__global__ __launch_bounds__(256)
void attnv_kernel(const float* __restrict__ attn, const u16* __restrict__ kvT,
                  u16* __restrict__ outT) {
    __shared__ float at[8][32][33];
    __shared__ u16 vs[8][256];
    int b = blockIdx.x >> 7, chunk = blockIdx.x & 127;
    int t = threadIdx.x;
    for (int idx = t; idx < 8192; idx += 256) {
        int hh = idx >> 10, rem = idx & 1023;
        at[hh][rem >> 5][rem & 31] = attn[(size_t)b * 8192 + idx];
    }
    int h = t >> 5, i = t & 31;
    int row0 = b * NPIX + chunk * 128;
    int rr = t >> 5, cc = (t & 31) * 8;
    for (int r8 = 0; r8 < 128; r8 += 8) {
        __syncthreads();
        *(uint4*)&vs[rr][cc] = *(const uint4*)(kvT + (size_t)(row0 + r8 + rr) * 512 + 256 + cc);
        __syncthreads();
#pragma unroll
        for (int r = 0; r < 8; ++r) {
            float a = 0.f;
#pragma unroll
            for (int j = 0; j < 32; j += 4) {
                uint2 vd = *(const uint2*)&vs[r][h * 32 + j];
                u16 v4[4]; *(uint2*)v4 = vd;
                a += at[h][i][j]     * bf2f(v4[0]);
                a += at[h][i][j + 1] * bf2f(v4[1]);
                a += at[h][i][j + 2] * bf2f(v4[2]);
                a += at[h][i][j + 3] * bf2f(v4[3]);
            }
            outT[(size_t)(row0 + r8 + r) * 256 + t] = f2bf(a);
        }
    }
}

// ---------------- transpose NHWC Fp back to NCHW, add hx, write out (flag-aware format)
__global__ __launch_bounds__(256)
void final_out(const u16* __restrict__ Fp, const u16* __restrict__ hx,
               const int* __restrict__ flag, u16* __restrict__ out) {
    int isf32 = *flag;
    __shared__ u16 T[64][72];
    int b = blockIdx.x >> 8;
    int n0 = (blockIdx.x & 255) * 64;
    int c0 = blockIdx.y * 64;
    int t = threadIdx.x;
#pragma unroll
    for (int l = 0; l < 2; ++l) {
        int idx = t + l * 256;
        int nl = idx >> 3, cch = (idx & 7) * 8;
        *(uint4*)&T[nl][cch] = *(const uint4*)(Fp + (size_t)(b * NPIX + n0 + nl) * 256 + c0 + cch);
    }
    __syncthreads();
#pragma unroll
    for (int l = 0; l < 2; ++l) {
        int idx = t + l * 256;
        int cl = idx >> 3, nch = (idx & 7) * 8;
        size_t g = (size_t)(b * DIM + c0 + cl) * NPIX + n0 + nch;
        float hv[8];
        load8(hx, g, isf32, hv);
        float r[8];
#pragma unroll
        for (int j = 0; j < 8; ++j) r[j] = bf2f(T[nch + j][cl]) + hv[j];
        if (isf32) {
            float* o = (float*)out + g;
            *(float4*)o       = make_float4(r[0], r[1], r[2], r[3]);
            *(float4*)(o + 4) = make_float4(r[4], r[5], r[6], r[7]);
        } else {
            u16 ov[8];
#pragma unroll
            for (int j = 0; j < 8; ++j) ov[j] = f2bf(r[j]);
            *(uint4*)(out + g) = *(uint4*)ov;
        }
    }
}

__global__ void ws_marker(u16* out) {
    if (threadIdx.x < 64) ((uint32_t*)out)[threadIdx.x] = 0x46402400u;  // 12345.0f pattern
}

extern "C" void kernel_launch(void* const* d_in, const int* in_sizes, int n_in,
                              void* d_out, int out_size, void* d_ws, size_t ws_size,
                              hipStream_t stream) {
    const u16* x    = (const u16*)d_in[0];
    const u16* hx   = (const u16*)d_in[1];
    u16* outp = (u16*)d_out;

    char* ws = (char*)d_ws;
    float* F = (float*)ws;
    float* mu_x   = F;
    float* rstd_x = F + 131072;
    float* mu_h   = F + 262144;
    float* rstd_h = F + 393216;
    float* qss    = F + 524288;
    float* kss    = F + 526336;
    float* qsc    = F + 528384;
    float* ksc    = F + 530432;
    float* G      = F + 532480;
    float* attn   = F + 598016;
    int*   dflag  = (int*)(F + 663552);
    u16*   W      = (u16*)(ws + 2752512);          // canonical bf16 params
    u16* R1 = (u16*)(ws + (((size_t)4)   << 20));   // 64 MiB
    u16* R2 = (u16*)(ws + (((size_t)68)  << 20));   // 64 MiB
    u16* R3 = (u16*)(ws + (((size_t)132) << 20));   // 128 MiB
    u16* R4 = (u16*)(ws + (((size_t)260) << 20));   // 128 MiB

    size_t need = ((size_t)388) << 20;
    if (ws_size < need) {
        ws_marker<<<1, 64, 0, stream>>>(outp);
        return;
    }

    // canonical param element offsets in W
    const int O_QW = 0, O_KVW = 65536, O_AOW = 196608, O_QB = 262144, O_KVB = 262400,
              O_AOB = 262912, O_LN1W = 263168, O_LN1B = 263424, O_LN2W = 263680,
              O_LN2B = 263936, O_QDWW = 264192, O_QDWB = 266496, O_KVDWW = 266752,
              O_KVDWB = 271360, O_PE1 = 271872, O_PE2 = 274176, O_TEMP = 276480;

    WArgs wa;
    const int srcidx[17] = {6, 10, 14, 7, 11, 15, 2, 3, 4, 5, 8, 9, 12, 13, 16, 17, 18};
    const int offs[17]   = {O_QW, O_KVW, O_AOW, O_QB, O_KVB, O_AOB, O_LN1W, O_LN1B,
                            O_LN2W, O_LN2B, O_QDWW, O_QDWB, O_KVDWW, O_KVDWB,
                            O_PE1, O_PE2, O_TEMP};
    const int ns[17]     = {65536, 131072, 65536, 256, 512, 256, 256, 256, 256, 256,
                            2304, 256, 4608, 512, 2304, 2304, 8};
    for (int i = 0; i < 17; ++i) { wa.src[i] = d_in[srcidx[i]]; wa.off[i] = offs[i]; wa.n[i] = ns[i]; }

    detect_dtype<<<1, 256, 0, stream>>>(x, dflag);
    convert_params<<<dim3(16, 17), 256, 0, stream>>>(wa, dflag, W);

    // zero sumsq accumulators + G (float idx 524288 .. 598016)
    hipMemsetAsync(ws + (size_t)524288 * 4, 0, (size_t)(598016 - 524288) * 4, stream);

    ln_stats<<<512, 256, 0, stream>>>(x, dflag, mu_x, rstd_x);
    ln_stats<<<512, 256, 0, stream>>>(hx, dflag, mu_h, rstd_h);

    ln_transpose<<<dim3(2048, 4), 256, 0, stream>>>(x, dflag, mu_x, rstd_x, W + O_LN1W, W + O_LN1B, R1);
    gemm_bf16<0><<<dim3(1024, 2), 256, 0, stream>>>(R1, W + O_QW, W + O_QB, nullptr, R2, 256);

    ln_transpose<<<dim3(2048, 4), 256, 0, stream>>>(hx, dflag, mu_h, rstd_h, W + O_LN2W, W + O_LN2B, R1);
    gemm_bf16<0><<<dim3(1024, 4), 256, 0, stream>>>(R1, W + O_KVW, W + O_KVB, nullptr, R3, 512);

    dwconv3_nhwc<<<16384, 256, 9 * 256 * 4, stream>>>(R2, 256, 0, W + O_QDWW, W + O_QDWB, R1, 256, 0, 256, 0);
    dwconv3_nhwc<<<32768, 256, 9 * 512 * 4, stream>>>(R3, 512, 0, W + O_KVDWW, W + O_KVDWB, R4, 512, 0, 512, 0);

    colsumsq<<<256, 256, 0, stream>>>(R1, 256, 0, qss);
    colsumsq<<<256, 256, 0, stream>>>(R4, 512, 0, kss);
    finalize_scales<<<8, 256, 0, stream>>>(qss, kss, qsc, ksc);

    gram_kernel<<<256, 256, 0, stream>>>(R1, R4, G);
    softmax32<<<64, 1024, 0, stream>>>(G, qsc, ksc, W + O_TEMP, attn);
    attnv_kernel<<<1024, 256, 0, stream>>>(attn, R4, R2);

    dwconv3_nhwc<<<16384, 256, 9 * 256 * 4, stream>>>(R4, 512, 256, W + O_PE1, nullptr, R3, 256, 0, 256, 1);
    dwconv3_nhwc<<<16384, 256, 9 * 256 * 4, stream>>>(R3, 256, 0, W + O_PE2, nullptr, R1, 256, 0, 256, 0);

    gemm_bf16<1><<<dim3(1024, 2), 256, 0, stream>>>(R2, W + O_AOW, W + O_AOB, R1, R3, 256);
    final_out<<<dim3(2048, 4), 256, 0, stream>>>(R3, hx, dflag, outp);
}